// Round 6
// baseline (655.291 us; speedup 1.0000x reference)
//
#include <hip/hip_runtime.h>
#include <hip/hip_cooperative_groups.h>

namespace cg = cooperative_groups;

#define NB    128
#define P     512
#define PP    262144            // P*P
#define TOT   33554432          // NB*PP
#define MAX_IT 100

// scratch in the TAIL of the dist_sqr output region (float offsets from scr)
#define SCR_W      0            // 262144 : |1/(s.s^T)+1e-5|
#define SCR_X      262144       // 196608 : copy of x
#define SCR_Y      458752       // 196608 : copy of y
#define SCR_CP     655360       // 2*128*4*512 = 524288 (dbuf col partials)
#define SCR_U      1179648      // 65536
#define SCR_V      1245184      // 65536
#define SCR_ERRP   1310720      // 2*512 (dbuf)
#define SCR_DONE   1311744      // flag (+pad)
#define SCR_FLOATS 1312000
#define DIST_KEEP  (TOT - SCR_FLOATS)   // 32242432, multiple of 4

__device__ __forceinline__ float bfbits(unsigned u) {
  union { unsigned b; float f; } x; x.b = u; return x.f;
}

__global__ void prep_kernel(const float* __restrict__ species,
                            const float* __restrict__ x, const float* __restrict__ y,
                            float* __restrict__ scr, float* __restrict__ cost) {
  int tid = blockIdx.x * 256 + threadIdx.x;      // grid covers PP
  if (tid < PP) {
    int i = tid >> 9, j = tid & (P - 1);
    const float* si = species + i * 8;
    const float* sj = species + j * 8;
    float g = 0.f;
#pragma unroll
    for (int k = 0; k < 8; ++k) g += si[k] * sj[k];
    scr[SCR_W + tid] = fabsf(1.0f / g + 1e-5f);
  }
  if (tid < NB * P * 3) {                        // 196608 < PP
    scr[SCR_X + tid] = x[tid];
    scr[SCR_Y + tid] = y[tid];
  }
  if (tid < NB * P) scr[SCR_U + tid] = 0.f;
  if (tid < NB) cost[tid] = 0.f;
  if (tid == 0) scr[SCR_DONE] = 0.f;
}

// writes C (all) and dist (prefix < DIST_KEEP)
__global__ void cmat_kernel(const float* __restrict__ x, const float* __restrict__ y,
                            const float* __restrict__ W,
                            float* __restrict__ C, float* __restrict__ dist) {
  int g = blockIdx.x * 256 + threadIdx.x;        // [0, TOT/4)
  int base = g << 2;
  int n = base >> 18;
  int r = base & (PP - 1);
  int i = r >> 9, j0 = r & (P - 1);
  const float* xp = x + ((n << 9) + i) * 3;
  float x0 = xp[0], x1 = xp[1], x2 = xp[2];
  const float* yp = y + ((n << 9) + j0) * 3;
  float4 w4 = *reinterpret_cast<const float4*>(W + r);
  float wv[4] = { w4.x, w4.y, w4.z, w4.w };
  float c[4], d[4];
#pragma unroll
  for (int q = 0; q < 4; ++q) {
    float dx = x0 - yp[q * 3 + 0];
    float dy = x1 - yp[q * 3 + 1];
    float dz = x2 - yp[q * 3 + 2];
    dx = rintf(dx) - dx; dy = rintf(dy) - dy; dz = rintf(dz) - dz;
    float ds = dx * dx + dy * dy + dz * dz;
    d[q] = ds;
    c[q] = ds * wv[q];
  }
  *reinterpret_cast<float4*>(C + base) = make_float4(c[0], c[1], c[2], c[3]);
  if (base < DIST_KEEP)
    *reinterpret_cast<float4*>(dist + base) = make_float4(d[0], d[1], d[2], d[3]);
}

__global__ void tail_kernel(const float* __restrict__ x, const float* __restrict__ y,
                            float* __restrict__ dist) {
  int idx = DIST_KEEP + blockIdx.x * 256 + threadIdx.x;   // grid covers SCR_FLOATS
  int n = idx >> 18;
  int r = idx & (PP - 1);
  int i = r >> 9, j = r & (P - 1);
  const float* xp = x + ((n << 9) + i) * 3;
  const float* yp = y + ((n << 9) + j) * 3;
  float ds = 0.f;
#pragma unroll
  for (int k = 0; k < 3; ++k) {
    float dd = xp[k] - yp[k];
    float per = rintf(dd) - dd;
    ds += per * per;
  }
  dist[idx] = ds;
}

// ---- FAST: 512 blocks x 256 threads (R1-proven coop config), K register-
// resident as bf16 pairs: 32 rows x 8 strided cols per thread = kreg[128].
// (256,2) => 2 blocks/CU target, 256-VGPR budget: ~185 used, NO SPILLS.
__global__ __launch_bounds__(256, 2)
void sink_b(float* __restrict__ scr) {
  cg::grid_group grid = cg::this_grid();
  const int tid  = threadIdx.x;
  const int lane = tid & 63;
  const int wid  = tid >> 6;               // 0..3
  const int bid  = blockIdx.x;             // 0..511
  const int n    = bid >> 2;
  const int qb   = bid & 3;                // quarter-batch: 128 rows

  float* u    = scr + SCR_U;
  float* cp   = scr + SCR_CP;
  float* errP = scr + SCR_ERRP;

  __shared__ float ys[P * 3];
  __shared__ float vLDS[P];
  __shared__ float cbuf[4][P];
  __shared__ float wdu[4];
  __shared__ float ebc;

  {
    const float* yb = scr + SCR_Y + (size_t)(n << 9) * 3;
    for (int q = tid; q < P * 3; q += 256) ys[q] = yb[q];
  }
  vLDS[tid] = 0.f; vLDS[tid + 256] = 0.f;
  __syncthreads();

  // K build: rows (qb<<7)+(wid<<5)+r (r=0..31), cols lane+64t (t=0..7)
  unsigned kreg[128];
#pragma unroll
  for (int r = 0; r < 32; ++r) {
    const int rl = (qb << 7) + (wid << 5) + r;
    const float* xp = scr + SCR_X + (size_t)((n << 9) + rl) * 3;
    const float x0 = xp[0], x1 = xp[1], x2 = xp[2];
    const float* Wr = scr + SCR_W + (rl << 9) + lane;
    unsigned kk[8];
#pragma unroll
    for (int t = 0; t < 8; ++t) {
      const int j = lane + (t << 6);
      float w = Wr[t << 6];
      float dx = x0 - ys[j * 3 + 0];
      float dy = x1 - ys[j * 3 + 1];
      float dz = x2 - ys[j * 3 + 2];
      dx = rintf(dx) - dx; dy = rintf(dy) - dy; dz = rintf(dz) - dz;
      float ds = dx * dx + dy * dy + dz * dz;
      float kf = __expf(-10.f * (ds * w));
      unsigned b = __float_as_uint(kf);
      kk[t] = (b + 0x7fffu + ((b >> 16) & 1u)) >> 16;   // RNE to bf16
    }
#pragma unroll
    for (int h = 0; h < 4; ++h)
      kreg[(r << 2) + h] = kk[2 * h] | (kk[2 * h + 1] << 16);
  }

  const float logmu = logf(1.0f / 512.0f + 1e-8f);
  const float muv   = 1.0f / 512.0f + 1e-8f;

  for (int it = 0; it < MAX_IT; ++it) {
    const int buf = it & 1;
    float ev[8], colacc[8];
#pragma unroll
    for (int t = 0; t < 8; ++t) {
      ev[t] = __expf(10.f * vLDS[lane + (t << 6)]);
      colacc[t] = 0.f;
    }
    float du = 0.f;
#pragma unroll
    for (int r = 0; r < 32; ++r) {
      float k[8];
#pragma unroll
      for (int h = 0; h < 4; ++h) {
        unsigned kw = kreg[(r << 2) + h];
        k[2 * h]     = bfbits(kw << 16);
        k[2 * h + 1] = bfbits(kw & 0xffff0000u);
      }
      float sA = k[0] * ev[0], sB = k[1] * ev[1];
      sA = fmaf(k[2], ev[2], sA); sB = fmaf(k[3], ev[3], sB);
      sA = fmaf(k[4], ev[4], sA); sB = fmaf(k[5], ev[5], sB);
      sA = fmaf(k[6], ev[6], sA); sB = fmaf(k[7], ev[7], sB);
      float s = sA + sB;
#pragma unroll
      for (int o = 32; o > 0; o >>= 1) s += __shfl_xor(s, o);
      const int rowg = (n << 9) + (qb << 7) + (wid << 5) + r;
      float uo = u[rowg];
      float un = 0.1f * (logmu - __logf(s));
      du += fabsf(un - uo);
      if (lane == 0) u[rowg] = un;
      float eu = __fdividef(muv, s);       // = exp(10*un)
#pragma unroll
      for (int t = 0; t < 8; ++t) colacc[t] = fmaf(k[t], eu, colacc[t]);
    }
#pragma unroll
    for (int t = 0; t < 8; ++t) cbuf[wid][lane + (t << 6)] = colacc[t];
    if (lane == 0) wdu[wid] = du;
    __syncthreads();

    {
      float s1 = cbuf[0][tid] + cbuf[1][tid] + cbuf[2][tid] + cbuf[3][tid];
      int c2 = tid + 256;
      float s2 = cbuf[0][c2] + cbuf[1][c2] + cbuf[2][c2] + cbuf[3][c2];
      float* cpd = cp + (buf << 18) + (n << 11) + (qb << 9);
      cpd[tid] = s1; cpd[c2] = s2;
      if (tid == 0) errP[(buf << 9) + bid] = wdu[0] + wdu[1] + wdu[2] + wdu[3];
    }
    grid.sync();

    {
      const float* cpb = cp + (buf << 18) + (n << 11);
      float sc1 = cpb[tid] + cpb[512 + tid] + cpb[1024 + tid] + cpb[1536 + tid];
      int c2 = tid + 256;
      float sc2 = cpb[c2] + cpb[512 + c2] + cpb[1024 + c2] + cpb[1536 + c2];
      vLDS[tid] = 0.1f * (logmu - __logf(sc1));
      vLDS[c2]  = 0.1f * (logmu - __logf(sc2));
    }
    if (wid == 0) {
      float e = 0.f;
#pragma unroll
      for (int q = 0; q < 8; ++q) e += errP[(buf << 9) + lane + (q << 6)];
#pragma unroll
      for (int o = 32; o > 0; o >>= 1) e += __shfl_xor(e, o);
      if (lane == 0) ebc = e;
    }
    __syncthreads();
    if (ebc < 12.8f) break;                // errTot/128 < 0.1, update applied
  }

  if (qb == 0) {
    scr[SCR_V + (n << 9) + tid]       = vLDS[tid];
    scr[SCR_V + (n << 9) + tid + 256] = vLDS[tid + 256];
  }
  if (tid == 0) scr[SCR_DONE] = 1.0f;
}

// ---- RESCUE: R2-proven envelope (512x512, low VGPR), K = exp(-10*C) from
// the f32 C matrix. Runs only if sink_b never executed (DONE flag).
__global__ __launch_bounds__(512, 4)
void sink_rescue(const float* __restrict__ Cm, float* __restrict__ scr) {
  if (scr[SCR_DONE] != 0.f) return;        // uniform early exit
  cg::grid_group grid = cg::this_grid();
  float* u    = scr + SCR_U;
  float* cp   = scr + SCR_CP;
  float* errP = scr + SCR_ERRP;

  const int tid  = threadIdx.x;
  const int lane = tid & 63;
  const int wid  = tid >> 6;
  const int bid  = blockIdx.x;
  const int n    = bid >> 2;
  const int rb   = bid & 3;
  const int row0 = (n << 9) + (rb << 7);

  __shared__ float vLDS[P];
  __shared__ float colsum[P];
  __shared__ float red[P];
  __shared__ float wdu[8];

  vLDS[tid] = 0.f;
  __syncthreads();

  const float logmu = logf(1.0f / 512.0f + 1e-8f);

  for (int it = 0; it < MAX_IT; ++it) {
    const int buf = it & 1;
    float ev[8], colacc[8];
#pragma unroll
    for (int t = 0; t < 8; ++t) {
      ev[t] = __expf(10.f * vLDS[(lane << 3) + t]);
      colacc[t] = 0.f;
    }
    colsum[tid] = 0.f;
    __syncthreads();

    float myDu = 0.f;
#pragma unroll 2
    for (int r = 0; r < 16; ++r) {
      int row = row0 + (wid << 4) + r;
      const float* Cr = Cm + ((size_t)row << 9) + (lane << 3);
      float4 ca = *reinterpret_cast<const float4*>(Cr);
      float4 cb = *reinterpret_cast<const float4*>(Cr + 4);
      float k[8];
      k[0] = __expf(-10.f * ca.x); k[1] = __expf(-10.f * ca.y);
      k[2] = __expf(-10.f * ca.z); k[3] = __expf(-10.f * ca.w);
      k[4] = __expf(-10.f * cb.x); k[5] = __expf(-10.f * cb.y);
      k[6] = __expf(-10.f * cb.z); k[7] = __expf(-10.f * cb.w);
      float s = 0.f;
#pragma unroll
      for (int t = 0; t < 8; ++t) s = fmaf(k[t], ev[t], s);
#pragma unroll
      for (int o = 32; o > 0; o >>= 1) s += __shfl_xor(s, o);
      float uo = u[row];
      float un = 0.1f * (logmu - __logf(s));
      myDu += fabsf(un - uo);
      if (lane == 0) u[row] = un;
      float eu = __expf(10.f * un);
#pragma unroll
      for (int t = 0; t < 8; ++t) colacc[t] = fmaf(k[t], eu, colacc[t]);
    }
#pragma unroll
    for (int t = 0; t < 8; ++t) atomicAdd(&colsum[(lane << 3) + t], colacc[t]);
    if (lane == 0) wdu[wid] = myDu;
    __syncthreads();

    cp[(buf << 18) + (n << 11) + (rb << 9) + tid] = colsum[tid];
    if (tid == 0) {
      errP[(buf << 9) + bid] = wdu[0] + wdu[1] + wdu[2] + wdu[3]
                             + wdu[4] + wdu[5] + wdu[6] + wdu[7];
    }
    grid.sync();

    const float* cpb = cp + (buf << 18) + (n << 11);
    float sc = cpb[tid] + cpb[512 + tid] + cpb[1024 + tid] + cpb[1536 + tid];
    float vc = 0.1f * (logmu - __logf(sc));

    red[tid] = errP[(buf << 9) + tid];
    __syncthreads();
#pragma unroll
    for (int o = 256; o > 0; o >>= 1) {
      if (tid < o) red[tid] += red[tid + o];
      __syncthreads();
    }
    float errTot = red[0];
    vLDS[tid] = vc;
    __syncthreads();
    if (errTot < 12.8f) break;
  }

  if (rb == 0) scr[SCR_V + (n << 9) + tid] = vLDS[tid];
}

// pi = exp((u_i + v_j - C)/eps), cost[n] += pi*C; C recomputed on the fly
__global__ __launch_bounds__(256)
void pi_kernel(const float* __restrict__ x, const float* __restrict__ y,
               const float* __restrict__ scr,
               float* __restrict__ pi, float* __restrict__ cost) {
  const int tid  = threadIdx.x;
  const int lane = tid & 63;
  const int wid  = tid >> 6;
  const int rowg = blockIdx.x * 4 + wid;
  const int n    = rowg >> 9;
  const int i    = rowg & (P - 1);

  __shared__ float ys[P * 3];
  {
    const float* yb = y + (size_t)(n << 9) * 3;
    for (int q = tid; q < P * 3; q += 256) ys[q] = yb[q];
  }
  __syncthreads();

  const int c0 = lane << 3;
  const float* xp = x + (size_t)rowg * 3;
  const float x0 = xp[0], x1 = xp[1], x2 = xp[2];
  const float uu = scr[SCR_U + rowg];
  const float* vp = scr + SCR_V + (n << 9) + c0;
  const float* Wr = scr + SCR_W + i * P + c0;

  float acc = 0.f;
  float4 po[2];
#pragma unroll
  for (int h = 0; h < 2; ++h) {
    float4 v4 = *reinterpret_cast<const float4*>(vp + h * 4);
    float4 w4 = *reinterpret_cast<const float4*>(Wr + h * 4);
    float vv[4] = { v4.x, v4.y, v4.z, v4.w };
    float wv[4] = { w4.x, w4.y, w4.z, w4.w };
    float pq[4];
#pragma unroll
    for (int q = 0; q < 4; ++q) {
      const int j = c0 + h * 4 + q;
      float dx = x0 - ys[j * 3 + 0];
      float dy = x1 - ys[j * 3 + 1];
      float dz = x2 - ys[j * 3 + 2];
      dx = rintf(dx) - dx; dy = rintf(dy) - dy; dz = rintf(dz) - dz;
      float ds = dx * dx + dy * dy + dz * dz;
      float c  = ds * wv[q];
      float p  = __expf((uu + vv[q] - c) * 10.f);
      pq[q] = p;
      acc = fmaf(p, c, acc);
    }
    po[h] = make_float4(pq[0], pq[1], pq[2], pq[3]);
  }
  float* Pr = pi + ((size_t)rowg << 9) + c0;
  *reinterpret_cast<float4*>(Pr)     = po[0];
  *reinterpret_cast<float4*>(Pr + 4) = po[1];

#pragma unroll
  for (int o = 32; o > 0; o >>= 1) acc += __shfl_xor(acc, o);
  __shared__ float wsum[4];
  if (lane == 0) wsum[wid] = acc;
  __syncthreads();
  if (tid == 0) atomicAdd(cost + n, wsum[0] + wsum[1] + wsum[2] + wsum[3]);
}

extern "C" void kernel_launch(void* const* d_in, const int* in_sizes, int n_in,
                              void* d_out, int out_size, void* d_ws, size_t ws_size,
                              hipStream_t stream) {
  const float* x = (const float*)d_in[0];
  const float* y = (const float*)d_in[1];
  const float* species = (const float*)d_in[2];

  float* out  = (float*)d_out;
  float* cost = out;                     // 128
  float* pi   = out + 128;               // TOT
  float* C    = pi + (size_t)TOT;        // TOT
  float* dist = C + (size_t)TOT;         // TOT
  float* scr  = dist + (size_t)DIST_KEEP;

  hipLaunchKernelGGL(prep_kernel, dim3(PP / 256), dim3(256), 0, stream,
                     species, x, y, scr, cost);
  hipLaunchKernelGGL(cmat_kernel, dim3(TOT / 4 / 256), dim3(256), 0, stream,
                     x, y, scr + SCR_W, C, dist);

  void* fargs[] = { (void*)&scr };
  hipLaunchCooperativeKernel((void*)sink_b, dim3(512), dim3(256),
                             fargs, 0, stream);

  void* rargs[] = { (void*)&C, (void*)&scr };
  hipLaunchCooperativeKernel((void*)sink_rescue, dim3(512), dim3(512),
                             rargs, 0, stream);

  hipLaunchKernelGGL(pi_kernel, dim3(NB * P / 4), dim3(256), 0, stream,
                     x, y, scr, pi, cost);
  hipLaunchKernelGGL(tail_kernel, dim3(SCR_FLOATS / 256), dim3(256), 0, stream,
                     x, y, dist);
}